// Round 8
// baseline (191.964 us; speedup 1.0000x reference)
//
#include <hip/hip_runtime.h>

// ---------------------------------------------------------------------------
// MNIST Langevin Encoder — round 8: copy overlapped with the WHOLE pipeline.
//   * copy = 1 float4/thread (block-turnover MLP, no NT-load/NT-store chains)
//   * copy blocks skip winner rows; langevin scatters those -> disjoint, so
//     copy chunks ride along gemm1, gemm2 AND langevin dispatches.
//   * gemm1 BN 512->256 (LDS 18KB) so copy blocks co-reside 8 blocks/CU.
// Pipeline: zero_win -> prep -> winner -> [gemm1|copy] -> [gemm2|copy] ->
//           [langevin+scatter|copy]
// ---------------------------------------------------------------------------

#define ZD 64
#define NSTEPS 25
#define EPSI 0.01f
#define K1 784
#define K1P 800
#define HSTR 512   // padded hidden stride (bf16 h)

typedef __attribute__((ext_vector_type(8))) short short8;
typedef __attribute__((ext_vector_type(4))) float f32x4;
typedef __attribute__((ext_vector_type(4))) int i32x4;

__device__ __forceinline__ unsigned short f2bf(float f) {
  union { float f; unsigned u; } v; v.f = f;
  return (unsigned short)((v.u + 0x7FFFu + ((v.u >> 16) & 1u)) >> 16);
}

__device__ __forceinline__ void gload_lds16(const void* g, void* l) {
  __builtin_amdgcn_global_load_lds(
      (const __attribute__((address_space(1))) void*)g,
      (__attribute__((address_space(3))) void*)l, 16, 0, 0);
}

// copy role: one float4 per thread; skip winner rows (langevin writes those).
__device__ __forceinline__ void copy_role(const f32x4* __restrict__ cache4,
                                          const int* __restrict__ winner,
                                          f32x4* __restrict__ out4,
                                          long e, long n4) {
  if (e < n4) {
    const long row = e >> 4;
    if (winner[row] == 0) {
      f32x4 v = cache4[e];
      __builtin_nontemporal_store(v, &out4[e]);
    }
  }
}

// ---------------- prep: W1 -> w1b[512][800] bf16 ; [W21;W22] -> wout[128][512]
__global__ __launch_bounds__(256) void prep_kernel(
    const float* __restrict__ W1, const float* __restrict__ W21,
    const float* __restrict__ W22, short* __restrict__ W1b,
    short* __restrict__ Wout) {
  const int t = blockIdx.x * 256 + threadIdx.x;
  const int NW1 = 512 * (K1P / 8);   // 51200 chunks of 8
  if (t < NW1) {
    const int n = t / (K1P / 8), k0 = (t % (K1P / 8)) * 8;
    short8 v = {0, 0, 0, 0, 0, 0, 0, 0};
    if (n < 400 && k0 < K1) {
      const float* s = W1 + (long)n * K1 + k0;
#pragma unroll
      for (int e = 0; e < 8; e++) v[e] = (short)f2bf(s[e]);
    }
    *(short8*)(W1b + (long)t * 8) = v;
  } else {
    const int q = t - NW1;           // wout: 128*64 = 8192 chunks
    if (q < 128 * 64) {
      const int n = q / 64, k0 = (q % 64) * 8;
      short8 v = {0, 0, 0, 0, 0, 0, 0, 0};
      if (k0 < 400) {
        const float* s = (n < 64) ? (W21 + (long)n * 400 + k0)
                                  : (W22 + (long)(n - 64) * 400 + k0);
#pragma unroll
        for (int e = 0; e < 8; e++) v[e] = (short)f2bf(s[e]);
      }
      *(short8*)(Wout + (long)q * 8) = v;
    }
  }
}

// ---------------- zero winner array ----------------------------------------
__global__ __launch_bounds__(256) void zero_win_kernel(i32x4* __restrict__ win4, int n4) {
  const int t = blockIdx.x * 256 + threadIdx.x;
  if (t < n4) win4[t] = (i32x4){0, 0, 0, 0};
}

// ---------------- winner: last duplicate index wins ------------------------
__global__ __launch_bounds__(256) void winner_kernel(
    const int* __restrict__ idx, int* __restrict__ winner, int B) {
  const int j = blockIdx.x * 256 + threadIdx.x;
  if (j < B) atomicMax(&winner[idx[j]], j + 1);
}

// ---------------- fused GEMM1 (BM=32, BN=256, BK=32) + copy chunk ----------
// gemm blocks [0, ngemm): bx>>1 = m-tile, bx&1 = n-half.
__global__ __launch_bounds__(256) void gemm1_copy_kernel(
    const float* __restrict__ X, const short* __restrict__ W1b,
    const float* __restrict__ b1, unsigned short* __restrict__ H,
    const f32x4* __restrict__ cache4, const int* __restrict__ winner,
    f32x4* __restrict__ out4, int ngemm, long cbase, long n4) {
  __shared__ short As[2 * 64 * 8];    // 2 KB, frag-major (2 row groups)
  __shared__ short Bs[16 * 64 * 8];   // 16 KB, frag-major (16 col groups)
  const int tid = threadIdx.x;

  if ((int)blockIdx.x >= ngemm) {
    const long e = cbase + (long)(blockIdx.x - ngemm) * 256 + tid;
    copy_role(cache4, winner, out4, e, n4);
    return;
  }

  const int w = tid >> 6;
  const int lane = tid & 63;
  const int m0 = (blockIdx.x >> 1) * 32;
  const int n0 = (blockIdx.x & 1) * 256;

  const f32x4 vzero = {0.f, 0.f, 0.f, 0.f};
  f32x4 acc[2][4];
#pragma unroll
  for (int i = 0; i < 2; i++)
#pragma unroll
    for (int j = 0; j < 4; j++) acc[i][j] = vzero;

  for (int k0 = 0; k0 < K1P; k0 += 32) {
    if (k0) __syncthreads();
    // A tile (32x32): reg-stage from fp32 x with on-the-fly cvt (tid<128).
    if (tid < 128) {
      const int row = m0 + (tid >> 6) * 16 + (lane & 15);
      const int gk = k0 + (lane >> 4) * 8;
      short8 av = {0, 0, 0, 0, 0, 0, 0, 0};
      if (gk < K1) {
        const float4 f0 = *(const float4*)(X + (long)row * K1 + gk);
        const float4 f1 = *(const float4*)(X + (long)row * K1 + gk + 4);
        av[0] = (short)f2bf(f0.x); av[1] = (short)f2bf(f0.y);
        av[2] = (short)f2bf(f0.z); av[3] = (short)f2bf(f0.w);
        av[4] = (short)f2bf(f1.x); av[5] = (short)f2bf(f1.y);
        av[6] = (short)f2bf(f1.z); av[7] = (short)f2bf(f1.w);
      }
      *(short8*)(As + (long)tid * 8) = av;
    }
    // B tile (256x32): global_load_lds, 4 groups per wave.
#pragma unroll
    for (int t = 0; t < 4; t++) {
      const int gn = w * 4 + t;
      const short* src = W1b + (long)(n0 + gn * 16 + (lane & 15)) * K1P +
                         k0 + (lane >> 4) * 8;
      gload_lds16(src, Bs + gn * 512);
    }
    __syncthreads();
    const short8* Ap = (const short8*)As;
    const short8* Bp = (const short8*)Bs;
    const short8 a0 = Ap[0 * 64 + lane];
    const short8 a1 = Ap[1 * 64 + lane];
#pragma unroll
    for (int j = 0; j < 4; j++) {
      const short8 b = Bp[(w * 4 + j) * 64 + lane];
      acc[0][j] = __builtin_amdgcn_mfma_f32_16x16x32_bf16(a0, b, acc[0][j], 0, 0, 0);
      acc[1][j] = __builtin_amdgcn_mfma_f32_16x16x32_bf16(a1, b, acc[1][j], 0, 0, 0);
    }
  }
  // epilogue: bias + relu + cvt -> bf16 h[row][col], stride 512
  const int colg = lane & 15;
  const int rowg = (lane >> 4) * 4;
#pragma unroll
  for (int j = 0; j < 4; j++) {
    const int col = n0 + w * 64 + j * 16 + colg;
    const float bias = (col < 400) ? b1[col] : 0.f;
#pragma unroll
    for (int i = 0; i < 2; i++) {
      const int rbase = m0 + i * 16 + rowg;
#pragma unroll
      for (int r = 0; r < 4; r++) {
        H[(long)(rbase + r) * HSTR + col] = f2bf(fmaxf(acc[i][j][r] + bias, 0.f));
      }
    }
  }
}

// ---------------- fused GEMM2 (BM=32, BN=128) + copy chunk -----------------
__global__ __launch_bounds__(256) void gemm2_copy_kernel(
    const unsigned short* __restrict__ H, const short* __restrict__ Wout,
    const float* __restrict__ b21, const float* __restrict__ b22,
    float* __restrict__ zloc, float* __restrict__ uarr,
    const f32x4* __restrict__ cache4, const int* __restrict__ winner,
    f32x4* __restrict__ out4, int ngemm, long cbase, long n4) {
  __shared__ short As[2 * 64 * 8];   // 2 KB
  __shared__ short Bs[8 * 64 * 8];   // 8 KB
  const int tid = threadIdx.x;

  if ((int)blockIdx.x >= ngemm) {
    const long e = cbase + (long)(blockIdx.x - ngemm) * 256 + tid;
    copy_role(cache4, winner, out4, e, n4);
    return;
  }

  const int w = tid >> 6;
  const int lane = tid & 63;
  const int m0 = blockIdx.x * 32;

  const f32x4 vzero = {0.f, 0.f, 0.f, 0.f};
  f32x4 acc[2][2];
#pragma unroll
  for (int i = 0; i < 2; i++)
#pragma unroll
    for (int j = 0; j < 2; j++) acc[i][j] = vzero;

  for (int k0 = 0; k0 < HSTR; k0 += 32) {
    if (k0) __syncthreads();
    if (w < 2) {  // A groups 0..1 via waves 0..1
      const unsigned short* src = H + (long)(m0 + w * 16 + (lane & 15)) * HSTR +
                                  k0 + (lane >> 4) * 8;
      gload_lds16(src, As + w * 512);
    }
#pragma unroll
    for (int t = 0; t < 2; t++) {  // B groups, 2 per wave
      const int gn = w * 2 + t;
      const short* src = Wout + (long)(gn * 16 + (lane & 15)) * HSTR +
                         k0 + (lane >> 4) * 8;
      gload_lds16(src, Bs + gn * 512);
    }
    __syncthreads();
    const short8* Ap = (const short8*)As;
    const short8* Bp = (const short8*)Bs;
    const short8 a0 = Ap[0 * 64 + lane];
    const short8 a1 = Ap[1 * 64 + lane];
#pragma unroll
    for (int j = 0; j < 2; j++) {
      const short8 b = Bp[(w * 2 + j) * 64 + lane];
      acc[0][j] = __builtin_amdgcn_mfma_f32_16x16x32_bf16(a0, b, acc[0][j], 0, 0, 0);
      acc[1][j] = __builtin_amdgcn_mfma_f32_16x16x32_bf16(a1, b, acc[1][j], 0, 0, 0);
    }
  }
  const int colg = lane & 15;
  const int rowg = (lane >> 4) * 4;
  float* outp = (w < 2) ? zloc : uarr;
  const float* bp = (w < 2) ? b21 : b22;
#pragma unroll
  for (int j = 0; j < 2; j++) {
    const int col = (w & 1) * 32 + j * 16 + colg;   // 0..63 within zloc or u
    const float bias = bp[col];
#pragma unroll
    for (int i = 0; i < 2; i++) {
      const int rbase = m0 + i * 16 + rowg;
#pragma unroll
      for (int r = 0; r < 4; r++) {
        outp[(long)(rbase + r) * ZD + col] = acc[i][j][r] + bias;
      }
    }
  }
}

// ---------------- fused Langevin + logq + winner scatter + copy chunk ------
__global__ __launch_bounds__(256) void langevin_copy_kernel(
    const float* __restrict__ zloc, const float* __restrict__ uarr,
    const float* __restrict__ cache, const int* __restrict__ idx,
    const float* __restrict__ noise, const int* __restrict__ winner,
    float* __restrict__ out_logq, float* __restrict__ out_z,
    float* __restrict__ out_cache, int B, int nlan, long cbase, long n4) {
  const int tid = threadIdx.x;

  if ((int)blockIdx.x >= nlan) {
    const long e = cbase + (long)(blockIdx.x - nlan) * 256 + tid;
    copy_role((const f32x4*)cache, winner, (f32x4*)out_cache, e, n4);
    return;
  }

  const int row = blockIdx.x * 4 + (tid >> 6);
  const int lane = tid & 63;
  const int i = idx[row];
  const float zl = zloc[(long)row * ZD + lane];
  const float uu = uarr[(long)row * ZD + lane];
  const float a = EPSI * expf(-2.f * uu);  // EPS * inv_var
  float z = cache[(long)i * ZD + lane];
  const float coef = sqrtf(2.f * EPSI);
  const float* np = noise + (long)row * ZD + lane;
  const long stride = (long)B * ZD;
#pragma unroll
  for (int s = 0; s < NSTEPS; s++) {
    z = z + a * (zl - z) + coef * np[(long)s * stride];
  }
  out_z[(long)row * ZD + lane] = z;
  // winner rows are skipped by all copy chunks -> no race, we own them
  if (winner[i] == row + 1) {
    out_cache[(long)i * ZD + lane] = z;
  }
  const float d = (z - zl) * expf(-uu);
  float t = -0.5f * d * d - uu - 0.91893853320467274178f;
#pragma unroll
  for (int off = 1; off < 64; off <<= 1) t += __shfl_xor(t, off);
  if (lane == 0) out_logq[row] = t;
}

extern "C" void kernel_launch(void* const* d_in, const int* in_sizes, int n_in,
                              void* d_out, int out_size, void* d_ws, size_t ws_size,
                              hipStream_t stream) {
  const float* x     = (const float*)d_in[0];
  const int*   idx   = (const int*)d_in[1];
  const float* W1    = (const float*)d_in[3];
  const float* b1    = (const float*)d_in[4];
  const float* W21   = (const float*)d_in[5];
  const float* b21   = (const float*)d_in[6];
  const float* W22   = (const float*)d_in[7];
  const float* b22   = (const float*)d_in[8];
  const float* cache = (const float*)d_in[9];
  const float* noise = (const float*)d_in[10];

  const int B  = in_sizes[1];            // 16384
  const int DS = in_sizes[9] / ZD;       // 1000000

  float* out_logq  = (float*)d_out;
  float* out_z     = out_logq + B;
  float* out_cache = out_z + (long)B * ZD;

  // workspace layout (~30.1 MB)
  unsigned short* h = (unsigned short*)d_ws;              // B*512 bf16
  short* w1b  = (short*)(h + (long)B * HSTR);             // 512*800 bf16
  short* wout = w1b + 512 * K1P;                          // 128*512 bf16
  float* zloc = (float*)(wout + 128 * HSTR);              // B*64 f32
  float* u    = zloc + (long)B * ZD;                      // B*64 f32
  int*   win  = (int*)(u + (long)B * ZD);                 // DS ints

  const int n4i = (DS + 3) / 4;                           // 250000 int4
  zero_win_kernel<<<(n4i + 255) / 256, 256, 0, stream>>>((i32x4*)win, n4i);

  const int prep_chunks = 512 * (K1P / 8) + 128 * 64;
  prep_kernel<<<(prep_chunks + 255) / 256, 256, 0, stream>>>(W1, W21, W22, w1b, wout);
  winner_kernel<<<(B + 255) / 256, 256, 0, stream>>>(idx, win, B);

  const long n4 = (long)DS * (ZD / 4);                    // 16M float4
  const int ncpy = (int)(n4 / 256);                       // 62500 copy blocks
  const int c1 = 32768;
  const int c2 = 8192;
  const int c3 = ncpy - c1 - c2;                          // 21540

  const int ngemm1 = (B / 32) * 2;                        // 1024
  gemm1_copy_kernel<<<ngemm1 + c1, 256, 0, stream>>>(
      x, w1b, b1, h, (const f32x4*)cache, win, (f32x4*)out_cache,
      ngemm1, 0L, n4);

  const int ngemm2 = B / 32;                              // 512
  gemm2_copy_kernel<<<ngemm2 + c2, 256, 0, stream>>>(
      h, wout, b21, b22, zloc, u, (const f32x4*)cache, win,
      (f32x4*)out_cache, ngemm2, (long)c1 * 256, n4);

  const int nlan = B / 4;                                 // 4096
  langevin_copy_kernel<<<nlan + c3, 256, 0, stream>>>(
      zloc, u, cache, idx, noise, win, out_logq, out_z, out_cache,
      B, nlan, (long)(c1 + c2) * 256, n4);
}